// Round 2
// baseline (457.866 us; speedup 1.0000x reference)
//
#include <hip/hip_runtime.h>
#include <hip/hip_bf16.h>

// FlowNetC correlation via bf16 MFMA band-GEMM.
// out[b, (dy+4)*9+(dx+4), y, x] = (1/256) * sum_c in1[b,c,y,x] * in2[b,c,y+dy,x+dx]
// B=8, C=256, H=96, W=128, MD=4.

#define B_ 8
#define C_ 256
#define H_ 96
#define W_ 128
#define HW_ 12288        // H*W
#define CHW_ 3145728     // C*H*W

// LDS geometry: per pixel, 32 bf16 channels (64 B) stored as 4 groups of 16 B,
// padded to 80 B stride so strided access patterns spread across banks.
#define PIXB 80
#define ROW1_B (64 * PIXB)                 // in1: 64 pixels (x-half)
#define ROW2_B (80 * PIXB)                 // in2: 64 + 2*8 halo pixels
#define LDSB_OFF ROW1_B
#define LDS_TOTAL (ROW1_B + 9 * ROW2_B)    // 62720 B -> 2 blocks/CU

typedef __attribute__((ext_vector_type(8))) short short8;   // 8 bf16 = 1 ds_read_b128
typedef __attribute__((ext_vector_type(4))) float f32x4;

// group-swizzle: breaks the stride-80 bank aliasing (lanes 8/16/24 apart)
__device__ __forceinline__ int swz(int g, int slot) {
    return g ^ (slot & 3) ^ ((slot >> 3) & 3);
}

__device__ __forceinline__ void cvt_store(void* dst, float f0, float f1, float f2, float f3) {
    __hip_bfloat162 a = __float22bfloat162_rn(float2{f0, f1});
    __hip_bfloat162 b = __float22bfloat162_rn(float2{f2, f3});
    union { __hip_bfloat162 h[2]; uint2 u; } p;
    p.h[0] = a; p.h[1] = b;
    *(uint2*)dst = p.u;   // 8 B: channels 4cq..4cq+3 of one pixel
}

__global__ __launch_bounds__(512, 4) void corr_mfma(
    const float* __restrict__ in1,
    const float* __restrict__ in2,
    float* __restrict__ out)
{
    __shared__ __align__(16) char lds[LDS_TOTAL];

    const int tid = threadIdx.x;

    // XCD-contiguous remap: 1536 blocks, 192 per XCD -> each XCD walks one
    // batch image in y-order (in2 9-row window ~1.2 MB stays L2-resident).
    const int g   = (blockIdx.x & 7) * 192 + (blockIdx.x >> 3);
    const int xh  = g & 1;             // x half: 0 -> x 0..63, 1 -> 64..127
    const int yy  = (g >> 1) % H_;
    const int b   = (g >> 1) / H_;
    const int xbase = xh * 64;

    // zero all of LDS once: halo columns / OOB rows remain zero for all chunks
    for (int off = tid * 16; off < LDS_TOTAL; off += 512 * 16)
        *(f32x4*)(lds + off) = f32x4{0.f, 0.f, 0.f, 0.f};

    // ---- staging ids: thread = (x pixel, channel-quad) ----
    const int xs = tid & 63;
    const int cq = tid >> 6;                // 0..7 -> channels 4cq..4cq+3 (wave-uniform)
    const int gq = cq >> 1, hq = cq & 1;

    // ---- compute ids: wave = (x-tile, u-tile) ----
    const int lane = tid & 63;
    const int wave = tid >> 6;
    const int ln   = lane & 15;
    const int qd   = lane >> 4;
    const int xt   = wave >> 1;             // 0..3
    const int tile = wave & 1;              // u-tile: u0 = x0 - 8 + 16*tile
    const int x0   = xbase + 16 * xt;

    const int xa   = 16 * xt + ln;                       // A pixel (local)
    const int offA = xa * PIXB + swz(qd, xa) * 16;
    const int slotB = 16 * xt + 16 * tile + ln;          // B pixel slot (0..79)
    const int offB  = LDSB_OFF + slotB * PIXB + swz(qd, slotB) * 16;

    f32x4 acc[9];
    #pragma unroll
    for (int s = 0; s < 9; ++s) acc[s] = f32x4{0.f, 0.f, 0.f, 0.f};

    const float* p1base = in1 + (size_t)b * CHW_ + (size_t)(4 * cq) * HW_
                              + (size_t)yy * W_ + (xbase + xs);
    const float* p2base = in2 + (size_t)b * CHW_ + (size_t)(4 * cq) * HW_;

    __syncthreads();   // zero-fill visible before first stage/read

    for (int kc = 0; kc < 8; ++kc) {       // 8 chunks x 32 channels
        // ---------------- stage global fp32 -> LDS bf16 ----------------
        {
            const float* s1 = p1base + (size_t)(32 * kc) * HW_;
            cvt_store(lds + xs * PIXB + swz(gq, xs) * 16 + hq * 8,
                      s1[0], s1[HW_], s1[2 * HW_], s1[3 * HW_]);
        }
        const float* p2c = p2base + (size_t)(32 * kc) * HW_;
        #pragma unroll
        for (int s = 0; s < 9; ++s) {
            const int ry = yy + s - 4;
            if (ry >= 0 && ry < H_) {                    // wave-uniform branch
                const float* srow = p2c + ry * W_;
                const int gx = xbase - 8 + xs;           // slot = xs
                if (gx >= 0 && gx < W_) {
                    const float* sp = srow + gx;
                    cvt_store(lds + LDSB_OFF + s * ROW2_B + xs * PIXB
                                  + swz(gq, xs) * 16 + hq * 8,
                              sp[0], sp[HW_], sp[2 * HW_], sp[3 * HW_]);
                }
                if (xs < 16) {                           // halo slots 64..79
                    const int slot2 = 64 + xs;
                    const int gx2 = xbase - 8 + slot2;
                    if (gx2 >= 0 && gx2 < W_) {
                        const float* sp = srow + gx2;
                        cvt_store(lds + LDSB_OFF + s * ROW2_B + slot2 * PIXB
                                      + swz(gq, slot2) * 16 + hq * 8,
                                  sp[0], sp[HW_], sp[2 * HW_], sp[3 * HW_]);
                    }
                }
            }
        }
        __syncthreads();
        // ---------------- MFMA: 1 A-frag, 9 B-frags ----------------
        short8 afr = *(const short8*)(lds + offA);
        #pragma unroll
        for (int s = 0; s < 9; ++s) {
            short8 bfr = *(const short8*)(lds + offB + s * ROW2_B);
            acc[s] = __builtin_amdgcn_mfma_f32_16x16x32_bf16(afr, bfr, acc[s], 0, 0, 0);
        }
        __syncthreads();
    }

    // ---------------- epilogue: band extraction + scaled store ----------------
    // D mapping (m89-verified): col n = lane&15, row m = (lane>>4)*4 + r.
    // x = x0 + m, u = u0 + n, dx = u - x = n - m - 8 + 16*tile; keep |dx| <= 4.
    const float scale = 1.0f / 256.0f;
    #pragma unroll
    for (int s = 0; s < 9; ++s) {
        #pragma unroll
        for (int r = 0; r < 4; ++r) {
            const int m  = qd * 4 + r;
            const int dx = ln - m - 8 + 16 * tile;
            if (dx >= -4 && dx <= 4) {
                const int x = x0 + m;
                out[(((size_t)b * 81 + (size_t)(s * 9 + dx + 4)) * H_ + yy) * W_ + x]
                    = acc[s][r] * scale;
            }
        }
    }
}

extern "C" void kernel_launch(void* const* d_in, const int* in_sizes, int n_in,
                              void* d_out, int out_size, void* d_ws, size_t ws_size,
                              hipStream_t stream) {
    const float* in1 = (const float*)d_in[0];
    const float* in2 = (const float*)d_in[1];
    float* out = (float*)d_out;

    // blocks = 8 b * 96 y * 2 x-halves = 1536 (6 balanced rounds on 256 CUs)
    corr_mfma<<<1536, 512, 0, stream>>>(in1, in2, out);
}

// Round 3
// 269.868 us; speedup vs baseline: 1.6966x; 1.6966x over previous
//
#include <hip/hip_runtime.h>
#include <hip/hip_bf16.h>

// FlowNetC correlation via bf16 MFMA band-GEMM, y-tiled for staging reuse.
// out[b, (dy+4)*9+(dx+4), y, x] = (1/256) * sum_c in1[b,c,y,x] * in2[b,c,y+dy,x+dx]
// B=8, C=256, H=96, W=128, MD=4.
//
// Block = (b, 8-row y-tile, 32-px x-quarter), 1024 threads (16 waves).
// LDS per 32-ch chunk: in1 8 rows x 32 px, in2 16 rows x 48 px (+-8 halo),
// 64 B per pixel-slot, 1024 slots = exactly 64 KB.
// Wave = (xt, ut, yrh): 2 x-subtiles x 2 u-tiles x 4 y-row-pairs.

#define B_ 8
#define C_ 256
#define H_ 96
#define W_ 128
#define HW_ 12288
#define CHW_ 3145728

#define IN1_OFF 0            // 8*32 = 256 slots
#define IN2_OFF 16384        // 256*64; in2: 16*48 = 768 slots
#define IN2_ROWB (48 * 64)   // bytes per in2 LDS row

typedef __attribute__((ext_vector_type(8))) short short8;
typedef __attribute__((ext_vector_type(4))) float f32x4;

// bank swizzle on the 16B channel-group within a 64B pixel slot
__device__ __forceinline__ int swz16(int g, int slot) {
    return (g ^ (slot & 3) ^ ((slot >> 2) & 3)) * 16;
}

// load 8 channels x 2 px (float2, stride HW) -> bf16 -> two b128 LDS writes
__device__ __forceinline__ void stage8(const float* __restrict__ sp, char* dst0, char* dst1) {
    float2 v[8];
    #pragma unroll
    for (int j = 0; j < 8; ++j) v[j] = *(const float2*)(sp + (size_t)j * HW_);
    union { __hip_bfloat162 h2[4]; short8 s8; } u0, u1;
    #pragma unroll
    for (int j = 0; j < 4; ++j) {
        u0.h2[j] = __float22bfloat162_rn(float2{v[2 * j].x, v[2 * j + 1].x});
        u1.h2[j] = __float22bfloat162_rn(float2{v[2 * j].y, v[2 * j + 1].y});
    }
    *(short8*)dst0 = u0.s8;
    *(short8*)dst1 = u1.s8;
}

__global__ __launch_bounds__(1024, 4) void corr_mfma2(
    const float* __restrict__ in1,
    const float* __restrict__ in2,
    float* __restrict__ out)
{
    __shared__ __align__(16) char lds[65536];

    const int tid = threadIdx.x;

    // XCD swizzle: blk%8 -> XCD; give each XCD one batch image, y-major walk.
    const int blk  = blockIdx.x;
    const int b    = blk & 7;
    const int rest = blk >> 3;        // 0..47
    const int yt   = rest >> 2;       // 0..11 (8-row tiles)
    const int xq   = rest & 3;        // 0..3  (32-px quarters)

    // zero LDS once: halo/OOB slots stay zero for every chunk
    #pragma unroll
    for (int k = 0; k < 4; ++k)
        *(f32x4*)(lds + tid * 16 + k * 16384) = f32x4{0.f, 0.f, 0.f, 0.f};

    // ---- compute ids ----
    const int lane = tid & 63;
    const int wv   = tid >> 6;              // 0..15
    const int xt   = wv & 1;
    const int ut   = (wv >> 1) & 1;
    const int yrh  = wv >> 2;               // 0..3 -> y rows 2*yrh, 2*yrh+1
    const int ln   = lane & 15;
    const int qd   = lane >> 4;

    const int pA   = 16 * xt + ln;                          // in1 slot px
    const int offA0 = IN1_OFF + ((2 * yrh) * 32 + pA) * 64 + swz16(qd, pA);
    const int pB   = 16 * (xt + ut) + ln;                   // in2 slot px (0..47)
    const int offB = IN2_OFF + ((2 * yrh) * 48 + pB) * 64 + swz16(qd, pB);

    const float* in1b = in1 + (size_t)b * CHW_;
    const float* in2b = in2 + (size_t)b * CHW_;

    f32x4 acc0[9], acc1[9];
    #pragma unroll
    for (int s = 0; s < 9; ++s) { acc0[s] = f32x4{0.f,0.f,0.f,0.f}; acc1[s] = f32x4{0.f,0.f,0.f,0.f}; }

    __syncthreads();   // zero-fill visible

    for (int kc = 0; kc < 8; ++kc) {
        const int ch0 = kc * 32;
        // ---------------- stage: 2048 slots, 2 per thread ----------------
        #pragma unroll
        for (int it = 0; it < 2; ++it) {
            const int S = tid + it * 1024;
            if (S < 1536) {            // in2: slot = (r*4+g)*24 + pp
                const int pp = S % 24;
                const int rg = S / 24;
                const int g  = rg & 3;
                const int r  = rg >> 2;          // 0..15
                const int px = pp * 2;
                const int gx = xq * 32 - 8 + px;
                const int ry = yt * 8 - 4 + r;
                if (gx >= 0 && gx <= 126 && ry >= 0 && ry < H_) {
                    const float* sp = in2b + (size_t)(ch0 + 8 * g) * HW_ + ry * W_ + gx;
                    const int slot = r * 48 + px;
                    char* d0 = lds + IN2_OFF + slot * 64 + swz16(g, slot);
                    char* d1 = lds + IN2_OFF + (slot + 1) * 64 + swz16(g, slot + 1);
                    stage8(sp, d0, d1);
                }
            } else {                   // in1: slot = (r*4+g)*16 + pp
                const int S1 = S - 1536;
                const int pp = S1 & 15;
                const int rg = S1 >> 4;
                const int g  = rg & 3;
                const int r  = rg >> 2;          // 0..7
                const int px = pp * 2;
                const int gx = xq * 32 + px;
                const int yy = yt * 8 + r;
                const float* sp = in1b + (size_t)(ch0 + 8 * g) * HW_ + yy * W_ + gx;
                const int slot = r * 32 + px;
                char* d0 = lds + IN1_OFF + slot * 64 + swz16(g, slot);
                char* d1 = lds + IN1_OFF + (slot + 1) * 64 + swz16(g, slot + 1);
                stage8(sp, d0, d1);
            }
        }
        __syncthreads();
        // ---------------- MFMA: 2 A-frags, rolling B-window ----------------
        short8 a0  = *(const short8*)(lds + offA0);
        short8 a1  = *(const short8*)(lds + offA0 + 32 * 64);
        short8 blo = *(const short8*)(lds + offB);
        #pragma unroll
        for (int s = 0; s < 9; ++s) {
            short8 bhi = *(const short8*)(lds + offB + (s + 1) * IN2_ROWB);
            acc0[s] = __builtin_amdgcn_mfma_f32_16x16x32_bf16(a0, blo, acc0[s], 0, 0, 0);
            acc1[s] = __builtin_amdgcn_mfma_f32_16x16x32_bf16(a1, bhi, acc1[s], 0, 0, 0);
            blo = bhi;
        }
        __syncthreads();
    }

    // ---------------- epilogue: band extraction ----------------
    // D: col n = ln -> u = xq*32 - 8 + 16*(xt+ut) + ln; row m = qd*4+r -> x = x0+m
    const float scale = 1.0f / 256.0f;
    const int x0 = xq * 32 + 16 * xt;
    const int ybase = yt * 8 + 2 * yrh;
    #pragma unroll
    for (int s = 0; s < 9; ++s) {
        #pragma unroll
        for (int yr = 0; yr < 2; ++yr) {
            const f32x4 a = yr ? acc1[s] : acc0[s];
            const int y = ybase + yr;
            #pragma unroll
            for (int r = 0; r < 4; ++r) {
                const int m  = qd * 4 + r;
                const int dx = ln - m - 8 + 16 * ut;
                if (dx >= -4 && dx <= 4) {
                    out[(((size_t)b * 81 + (size_t)(s * 9 + dx + 4)) * H_ + y) * W_ + (x0 + m)]
                        = a[r] * scale;
                }
            }
        }
    }
}

extern "C" void kernel_launch(void* const* d_in, const int* in_sizes, int n_in,
                              void* d_out, int out_size, void* d_ws, size_t ws_size,
                              hipStream_t stream) {
    const float* in1 = (const float*)d_in[0];
    const float* in2 = (const float*)d_in[1];
    float* out = (float*)d_out;

    // 8 b x 12 y-tiles x 4 x-quarters = 384 blocks
    corr_mfma2<<<384, 1024, 0, stream>>>(in1, in2, out);
}